// Round 4
// baseline (64.209 us; speedup 1.0000x reference)
//
#include <hip/hip_runtime.h>

#define CH 64
#define NN 56
#define XS (NN*NN)        // 3136 floats per channel image
#define RPB 7             // output rows per block
#define TR  8             // t4 row slots (RPB + 1)

// out[i,m,l] = g1[i,0]*t4[i,(m-1)%56,l] + g1[i,1]*t4[i,(m-2)%56,l]
// t4[i,n,l]  = sum_j sum_k g2[i,j,k] * x[j,n,l+k-1]   (zero-pad in l)
//
// Block = (channel i, group of 7 output rows), with the 64-channel reduction
// SPLIT across two thread-planes (j-halves) that combine through LDS:
//   512 threads = 2 j-halves x 8 row-slots x 32 lanes.
// This halves each thread's serial load chain (32 loads, unroll-8) and with
// grid=512 gives 16 waves/CU (4/SIMD) to hide L2/L3 latency — the remaining
// kernel cost is latency-bound, not throughput-bound.
__global__ __launch_bounds__(512) void fused_shift_conv4(
    const float* __restrict__ x,
    const float* __restrict__ g1,
    const float* __restrict__ g2,
    float* __restrict__ out)
{
    __shared__ float t4p[2][TR][NN];   // partial t4 per j-half

    const int i  = blockIdx.x >> 3;    // output channel 0..63
    const int g  = blockIdx.x & 7;     // row group 0..7
    const int r0 = g * RPB;

    const int tid = threadIdx.x;
    const int jh  = tid >> 8;          // j-half 0/1
    const int wv  = (tid >> 5) & 7;    // row slot 0..7
    const int lr  = tid & 31;          // lane within row

    const int n = (r0 - 2 + wv + NN) % NN;   // t4 row (wraps mod 56)

    const bool act = (lr < 28);
    const int  c   = (act ? lr : 27) * 2;    // clamped column base (even)
    const bool mL  = (lr == 0);              // col 0 has no left tap
    const bool mH  = (lr == 27);             // col 55 has no right tap

    const float* xp = x + n * NN + c + jh * (32 * XS);
    const float* wp = g2 + i * (CH * 3) + jh * (32 * 3);   // uniform -> s_load

    float ax = 0.f, ay = 0.f;

    #pragma unroll 8
    for (int j = 0; j < 32; ++j) {
        float2 v = *(const float2*)(xp + j * XS);
        float xl = __shfl_up(v.y, 1);          // x[c-1] from lane-1
        float xh = __shfl_down(v.x, 1);        // x[c+2] from lane+1
        xl = mL ? 0.f : xl;
        xh = mH ? 0.f : xh;
        const float w0 = wp[3*j+0], w1 = wp[3*j+1], w2 = wp[3*j+2];
        ax = fmaf(xl,  w0, ax);
        ax = fmaf(v.x, w1, ax);
        ax = fmaf(v.y, w2, ax);
        ay = fmaf(v.x, w0, ay);
        ay = fmaf(v.y, w1, ay);
        ay = fmaf(xh,  w2, ay);
    }

    if (act) *(float2*)&t4p[jh][wv][c] = make_float2(ax, ay);
    __syncthreads();

    if (jh == 0 && wv < RPB && act) {
        const float b0 = g1[i*2+0], b1 = g1[i*2+1];
        const float2 pA0 = *(const float2*)&t4p[0][wv+1][c];  // row r0+wv-1
        const float2 pA1 = *(const float2*)&t4p[1][wv+1][c];
        const float2 pB0 = *(const float2*)&t4p[0][wv][c];    // row r0+wv-2
        const float2 pB1 = *(const float2*)&t4p[1][wv][c];
        float2 o;
        o.x = fmaf(b0, pA0.x + pA1.x, b1 * (pB0.x + pB1.x));
        o.y = fmaf(b0, pA0.y + pA1.y, b1 * (pB0.y + pB1.y));
        *(float2*)&out[i*XS + (r0 + wv)*NN + c] = o;
    }
}

extern "C" void kernel_launch(void* const* d_in, const int* in_sizes, int n_in,
                              void* d_out, int out_size, void* d_ws, size_t ws_size,
                              hipStream_t stream) {
    const float* x  = (const float*)d_in[0];
    const float* w1 = (const float*)d_in[1];
    const float* w2 = (const float*)d_in[2];
    float* out      = (float*)d_out;

    dim3 grid(64 * 8);     // 64 channels x 8 row-groups = 512 blocks (2/CU)
    dim3 block(512);       // 2 j-halves x 8 row-slots x 32 lanes
    hipLaunchKernelGGL(fused_shift_conv4, grid, block, 0, stream, x, w1, w2, out);
}